// Round 11
// baseline (65.528 us; speedup 1.0000x reference)
//
#include <hip/hip_runtime.h>

// Problem: B=4, L=256, D=768, OUT=256
//   out[b,i,j,o] = pi[b,i,o] + pj[b,j,o] + bias[o]
// out: 268 MB f32. bcast is 90% of runtime; fill does 6.9 TB/s, we do ~5.2.
//
// R11: bcast v7 = GRID-STRIDE dense-front sweep (fill-mimic addressing, full
// occupancy). All 524288 threads write one contiguous 8MB front per step,
// 32 steps — tests DRAM row/bank locality of the instantaneous write pattern
// (the last untested difference vs fillBuffer; per-block chunking = 2048
// scattered 1KB fronts). o4, j are per-thread constants; r = n*32 + tid>>14.
// prep/mfma unchanged from R10 (proven: 56.7 total, absmax 0.031).
//
// ws layout: P f32[2][1024][256] | Afrag bf16[64*24*64*8] | Bfrag bf16[32*24*64*8]

#define DDIM 768
#define P_HALF (1024 * 256)
#define KS 24              // K-steps of 32
#define MT 64              // 16-row A tiles (M=1024)
#define NT 32              // 16-col B tiles (N=512)

typedef float f4 __attribute__((ext_vector_type(4)));
typedef __bf16 bf16;
typedef bf16 bf16x8 __attribute__((ext_vector_type(8)));

// ---- prep: build A/B bf16 fragment arrays (R10 form) ----
__global__ __launch_bounds__(256) void k_prep(const float* __restrict__ text,
                                              const float* __restrict__ W,
                                              bf16* __restrict__ Af,
                                              bf16* __restrict__ Bf) {
    const int l = threadIdx.x & 63;
    const int kb = (l >> 4) * 4;            // k sub-base within 32
    if (blockIdx.x < 384) {
        const int g  = blockIdx.x * 4 + (threadIdx.x >> 6);   // 0..1535
        const int mt = g / KS, ks = g % KS;
        const int row = mt * 16 + (l & 15);
        const float* src = text + (size_t)row * DDIM + ks * 32 + kb;
        f4 lo = *(const f4*)(src);
        f4 hi = *(const f4*)(src + 16);
        bf16x8 v;
#pragma unroll
        for (int e = 0; e < 4; ++e) { v[e] = (bf16)lo[e]; v[e + 4] = (bf16)hi[e]; }
        *(bf16x8*)(Af + ((size_t)g * 64 + l) * 8) = v;
    } else {
        const int g  = (blockIdx.x - 384) * 4 + (threadIdx.x >> 6);  // 0..767
        const int nt = g / KS, ks = g % KS;
        const int n  = nt * 16 + (l & 15);
        const int r  = (n < 256) ? n : (n - 256);
        const int kc = (n < 256) ? 0 : DDIM;
        const float* src = W + (size_t)r * 1536 + kc + ks * 32 + kb;
        f4 lo = *(const f4*)(src);
        f4 hi = *(const f4*)(src + 16);
        bf16x8 v;
#pragma unroll
        for (int e = 0; e < 4; ++e) { v[e] = (bf16)lo[e]; v[e + 4] = (bf16)hi[e]; }
        *(bf16x8*)(Bf + ((size_t)g * 64 + l) * 8) = v;
    }
}

// ---- MFMA GEMM (R10 form): C[1024][512] = A x B, bias folded into pi ----
__global__ __launch_bounds__(256) void k_mfma(const bf16* __restrict__ Af,
                                              const bf16* __restrict__ Bf,
                                              const float* __restrict__ bias,
                                              float* __restrict__ P) {
    const int l   = threadIdx.x & 63;
    const int wid = blockIdx.x * 4 + (threadIdx.x >> 6);
    const int mt  = wid & 63;
    const int nt  = wid >> 6;
    const bf16x8* ap = (const bf16x8*)Af + (size_t)(mt * KS) * 64 + l;
    const bf16x8* bp = (const bf16x8*)Bf + (size_t)(nt * KS) * 64 + l;
    f4 acc = (f4)0.0f;
#pragma unroll 6
    for (int ks = 0; ks < KS; ++ks) {
        bf16x8 a = ap[ks * 64];
        bf16x8 b = bp[ks * 64];
        acc = __builtin_amdgcn_mfma_f32_16x16x32_bf16(a, b, acc, 0, 0, 0);
    }
    const int n    = nt * 16 + (l & 15);
    const int rb   = mt * 16 + (l >> 4) * 4;
    if (n < 256) {                           // pj half
        float* p = P + (size_t)rb * 256 + n;
#pragma unroll
        for (int r = 0; r < 4; ++r) p[(size_t)r * 256] = acc[r];
    } else {                                 // pi half + bias
        const float bv = bias[n - 256];
        float* p = P + (size_t)P_HALF + (size_t)rb * 256 + (n - 256);
#pragma unroll
        for (int r = 0; r < 4; ++r) p[(size_t)r * 256] = acc[r] + bv;
    }
}

// ---- broadcast add v7: grid-stride dense-front sweep ----
// 2048 blocks x 256 thr = 524288 threads. f4 index g = n*2^19 + tid_flat.
// Per thread: o4 = (tid&63)*4 and j = (tid>>6)&255 are CONSTANT;
// r = n*32 + (tid>>14). Each step writes one dense 8MB front.
__global__ __launch_bounds__(256) void k_bcast(const float* __restrict__ P,
                                               float* __restrict__ out) {
    const int tid = blockIdx.x * 256 + threadIdx.x;      // 0..524287
    const int o4  = (tid & 63) * 4;
    const int j   = (tid >> 6) & 255;
    const int t14 = tid >> 14;                            // 0..31
    const float* pi0 = P + P_HALF + o4;
    const float* pj0 = P + (size_t)j * 256 + o4;          // + b*65536 per iter
    float* o0 = out + (size_t)tid * 4;
#pragma unroll
    for (int n = 0; n < 32; ++n) {
        const int r = n * 32 + t14;                       // 0..1023
        const int b = r >> 8;
        f4 pi4 = *(const f4*)(pi0 + (size_t)r * 256);     // L2-hit
        f4 pj4 = *(const f4*)(pj0 + (size_t)b * 65536);   // L2-hit
        *(f4*)(o0 + (size_t)n * 2097152) = pi4 + pj4;     // dense 8MB front/step
    }
}

extern "C" void kernel_launch(void* const* d_in, const int* in_sizes, int n_in,
                              void* d_out, int out_size, void* d_ws, size_t ws_size,
                              hipStream_t stream) {
    const float* text   = (const float*)d_in[0];   // [4][256][768]
    const float* weight = (const float*)d_in[1];   // [256][1536]
    const float* bias   = (const float*)d_in[2];   // [256]
    float* out = (float*)d_out;                    // [4][256][256][256]
    float* P   = (float*)d_ws;                     // [2][1024][256] f32
    bf16* Af   = (bf16*)(P + 2 * P_HALF);          // [64*24*64*8]
    bf16* Bf   = Af + (size_t)MT * KS * 64 * 8;    // [32*24*64*8]

    k_prep<<<576, 256, 0, stream>>>(text, weight, Af, Bf);
    k_mfma<<<512, 256, 0, stream>>>(Af, Bf, bias, P);
    k_bcast<<<2048, 256, 0, stream>>>(P, out);
}

// Round 12
// 56.527 us; speedup vs baseline: 1.1592x; 1.1592x over previous
//
#include <hip/hip_runtime.h>

// Problem: B=4, L=256, D=768, OUT=256
//   out[b,i,j,o] = pi[b,i,o] + pj[b,j,o] + bias[o]
// out: 268 MB f32 -> write-BW bound. TERMINAL (R10 form, proven 56.7us):
//   k_prep:  text/weight -> bf16 MFMA fragments (~1.5us)
//   k_mfma:  2048 waves x one 16x16 C-tile, no LDS/syncs (~2.5us)
//   k_bcast: R4 form — 2048 blocks, private 128KB chunks, plain stores
//            (~50us = 5.2 TB/s; structural after 7 geometry probes:
//            nt-stores/dense-front/long-streams/low-occ all worse or neutral)
// Composed floor = 50 + 1.5 + 2.5 + ~3 gaps ~= 57us == measured.
//
// ws layout: P f32[2][1024][256] | Afrag bf16[64*24*64*8] | Bfrag bf16[32*24*64*8]

#define DDIM 768
#define P_HALF (1024 * 256)
#define KS 24              // K-steps of 32
#define MT 64              // 16-row A tiles (M=1024)
#define NT 32              // 16-col B tiles (N=512)

typedef float f4 __attribute__((ext_vector_type(4)));
typedef __bf16 bf16;
typedef bf16 bf16x8 __attribute__((ext_vector_type(8)));

// ---- prep: build A/B bf16 fragment arrays ----
// Afrag[(mt*KS+ks)*64 + l][e] = text[mt*16 + (l&15)][ks*32 + (l>>4)*4 + (e&3) + (e>>2)*16]
// Bfrag[(nt*KS+ks)*64 + l][e] = B[k][n]: n<256 -> weight[n][k]; else weight[n-256][768+k]
__global__ __launch_bounds__(256) void k_prep(const float* __restrict__ text,
                                              const float* __restrict__ W,
                                              bf16* __restrict__ Af,
                                              bf16* __restrict__ Bf) {
    const int l = threadIdx.x & 63;
    const int kb = (l >> 4) * 4;            // k sub-base within 32
    if (blockIdx.x < 384) {
        const int g  = blockIdx.x * 4 + (threadIdx.x >> 6);   // 0..1535
        const int mt = g / KS, ks = g % KS;
        const int row = mt * 16 + (l & 15);
        const float* src = text + (size_t)row * DDIM + ks * 32 + kb;
        f4 lo = *(const f4*)(src);
        f4 hi = *(const f4*)(src + 16);
        bf16x8 v;
#pragma unroll
        for (int e = 0; e < 4; ++e) { v[e] = (bf16)lo[e]; v[e + 4] = (bf16)hi[e]; }
        *(bf16x8*)(Af + ((size_t)g * 64 + l) * 8) = v;
    } else {
        const int g  = (blockIdx.x - 384) * 4 + (threadIdx.x >> 6);  // 0..767
        const int nt = g / KS, ks = g % KS;
        const int n  = nt * 16 + (l & 15);
        const int r  = (n < 256) ? n : (n - 256);
        const int kc = (n < 256) ? 0 : DDIM;
        const float* src = W + (size_t)r * 1536 + kc + ks * 32 + kb;
        f4 lo = *(const f4*)(src);
        f4 hi = *(const f4*)(src + 16);
        bf16x8 v;
#pragma unroll
        for (int e = 0; e < 4; ++e) { v[e] = (bf16)lo[e]; v[e + 4] = (bf16)hi[e]; }
        *(bf16x8*)(Bf + ((size_t)g * 64 + l) * 8) = v;
    }
}

// ---- MFMA GEMM: C[1024][512] = A x B, bias folded into pi half ----
// 512 blocks x 256 thr = 2048 waves; wave wid: mt = wid&63, nt = wid>>6.
// Per kstep: 2 coalesced b128 loads (lane-contiguous) + 1 MFMA. No LDS.
__global__ __launch_bounds__(256) void k_mfma(const bf16* __restrict__ Af,
                                              const bf16* __restrict__ Bf,
                                              const float* __restrict__ bias,
                                              float* __restrict__ P) {
    const int l   = threadIdx.x & 63;
    const int wid = blockIdx.x * 4 + (threadIdx.x >> 6);
    const int mt  = wid & 63;
    const int nt  = wid >> 6;
    const bf16x8* ap = (const bf16x8*)Af + (size_t)(mt * KS) * 64 + l;
    const bf16x8* bp = (const bf16x8*)Bf + (size_t)(nt * KS) * 64 + l;
    f4 acc = (f4)0.0f;
#pragma unroll 6
    for (int ks = 0; ks < KS; ++ks) {
        bf16x8 a = ap[ks * 64];
        bf16x8 b = bp[ks * 64];
        acc = __builtin_amdgcn_mfma_f32_16x16x32_bf16(a, b, acc, 0, 0, 0);
    }
    const int n    = nt * 16 + (l & 15);
    const int rb   = mt * 16 + (l >> 4) * 4;
    if (n < 256) {                           // pj half
        float* p = P + (size_t)rb * 256 + n;
#pragma unroll
        for (int r = 0; r < 4; ++r) p[(size_t)r * 256] = acc[r];
    } else {                                 // pi half + bias
        const float bv = bias[n - 256];
        float* p = P + (size_t)P_HALF + (size_t)rb * 256 + (n - 256);
#pragma unroll
        for (int r = 0; r < 4; ++r) p[(size_t)r * 256] = acc[r] + bv;
    }
}

// ---- broadcast add (R4 form, proven): 2048 blocks, j-step-4, plain stores ----
__global__ __launch_bounds__(256) void k_bcast(const float* __restrict__ P,
                                               float* __restrict__ out) {
    const int bid  = blockIdx.x;
    const int r    = bid >> 1;
    const int half = bid & 1;
    const int b    = r >> 8;
    const int o4 = (threadIdx.x & 63) * 4;
    const int jg = threadIdx.x >> 6;
    const f4 pi4 = *(const f4*)(P + (size_t)P_HALF + (size_t)r * 256 + o4);
    const float* pjb = P + (size_t)b * 65536;        // pj[b*256 + j][o]
    float* outr = out + (size_t)r * 65536;
    const int j0 = half * 128 + jg;
#pragma unroll 8
    for (int j = j0; j < j0 + 128 - jg; j += 4) {
        f4 pj4 = *(const f4*)(pjb + j * 256 + o4);   // L2-resident
        f4 v = pi4 + pj4;
        *(f4*)(outr + j * 256 + o4) = v;             // plain store, 1KB/wave
    }
}

extern "C" void kernel_launch(void* const* d_in, const int* in_sizes, int n_in,
                              void* d_out, int out_size, void* d_ws, size_t ws_size,
                              hipStream_t stream) {
    const float* text   = (const float*)d_in[0];   // [4][256][768]
    const float* weight = (const float*)d_in[1];   // [256][1536]
    const float* bias   = (const float*)d_in[2];   // [256]
    float* out = (float*)d_out;                    // [4][256][256][256]
    float* P   = (float*)d_ws;                     // [2][1024][256] f32
    bf16* Af   = (bf16*)(P + 2 * P_HALF);          // [64*24*64*8]
    bf16* Bf   = Af + (size_t)MT * KS * 64 * 8;    // [32*24*64*8]

    k_prep<<<576, 256, 0, stream>>>(text, weight, Af, Bf);
    k_mfma<<<512, 256, 0, stream>>>(Af, Bf, bias, P);
    k_bcast<<<2048, 256, 0, stream>>>(P, out);
}